// Round 4
// baseline (50004.520 us; speedup 1.0000x reference)
//
#include <hip/hip_runtime.h>
#include <hip/hip_bf16.h>

// Problem constants
#define Bn 256
#define Tn 336
#define KE 16
#define Hn 512
#define Pn 256

typedef __attribute__((ext_vector_type(8))) __bf16 bf16x8;
typedef __attribute__((ext_vector_type(4))) float f32x4;

#define MFMA(a, b, c) __builtin_amdgcn_mfma_f32_16x16x32_bf16((a), (b), (c), 0, 0, 0)

// ---------------- pack kernels (once per launch) ----------------

// Wh [512,256] (k,n) -> WhT hi/lo [256][512] (n,k)
__global__ void pack_wh(const float* __restrict__ Wh, __bf16* __restrict__ hi,
                        __bf16* __restrict__ lo) {
    int i = blockIdx.x * 256 + threadIdx.x;  // 512*256
    int k = i >> 8, n = i & 255;
    float v = Wh[i];
    __bf16 h = (__bf16)v;
    hi[n * 512 + k] = h;
    lo[n * 512 + k] = (__bf16)(v - (float)h);
}

// Wx [17,256] -> WxTP [256][32] (n,k) zero-padded
__global__ void pack_wx(const float* __restrict__ Wx, __bf16* __restrict__ out) {
    int i = blockIdx.x * 256 + threadIdx.x;  // 256*32
    int n = i >> 5, k = i & 31;
    out[i] = (__bf16)((k < 17) ? Wx[k * 256 + n] : 0.f);
}

// same-layout fp32 -> bf16 hi/lo split
__global__ void pack_split(const float* __restrict__ in, __bf16* __restrict__ hi,
                           __bf16* __restrict__ lo, int n) {
    int i = blockIdx.x * 256 + threadIdx.x;
    if (i >= n) return;
    float v = in[i];
    __bf16 h = (__bf16)v;
    hi[i] = h;
    lo[i] = (__bf16)(v - (float)h);
}

// Xin packed time-major: [T][B][32] bf16, k=0 -> x_l, k=1..16 -> x_ext, else 0
__global__ void pack_xin(const float* __restrict__ xl, const float* __restrict__ xe,
                         __bf16* __restrict__ out) {
    int i = blockIdx.x * 256 + threadIdx.x;  // 336*256*32
    int k = i & 31, b = (i >> 5) & 255, t = i >> 13;
    float v = 0.f;
    if (k == 0) v = xl[b * Tn + t];
    else if (k < 17) v = xe[(b * Tn + t) * KE + (k - 1)];
    out[i] = (__bf16)v;
}

// ---------------- persistent GRU kernel ----------------
// grid = 256 blocks (1/CU), block = 512 threads (8 waves).
// group g = bid&7 (XCD-affine), 32 blocks/group, batch rows [g*32, g*32+32).
// block l = bid>>3 owns hidden units [16l, 16l+16).
// waves 0..5: (m = w&1 row-halves, gate g = w>>1) — W_hh B-frags in registers.
// wave 6: the block's x' tile (cols [16*(l>>1)..+16), rows [16*(l&1)..+16)).
// wave 7: staging/elementwise only.

// group barrier: device-scope atomic arrive + spin on monotone counter
#define GBAR(TGT)                                                                   \
    do {                                                                            \
        __threadfence();                                                            \
        __syncthreads();                                                            \
        if (tid == 0) {                                                             \
            __hip_atomic_fetch_add(cg, 1, __ATOMIC_RELEASE,                         \
                                   __HIP_MEMORY_SCOPE_AGENT);                       \
            while (__hip_atomic_load(cg, __ATOMIC_ACQUIRE,                          \
                                     __HIP_MEMORY_SCOPE_AGENT) < (TGT)) {           \
                __builtin_amdgcn_s_sleep(1);                                        \
            }                                                                       \
        }                                                                           \
        __syncthreads();                                                            \
        __threadfence();                                                            \
    } while (0)

__global__ __launch_bounds__(512, 2) void gru_persist(
    const __bf16* __restrict__ WhT_hi, const __bf16* __restrict__ WhT_lo,
    const __bf16* __restrict__ WxTP,
    const __bf16* __restrict__ Wih_hi, const __bf16* __restrict__ Wih_lo,
    const __bf16* __restrict__ Whh_hi, const __bf16* __restrict__ Whh_lo,
    const __bf16* __restrict__ XinP,
    const float* __restrict__ b_t, const float* __restrict__ b_ih,
    const float* __restrict__ b_hh,
    __bf16* xp, __bf16* hbf,     // NOT restrict: read+written in-kernel
    int* cnt, float* __restrict__ out)
{
    __shared__ __align__(16) char lds[57344];
    // [0,32768):      hT  32 rows x 1024B (bf16 k=512), XOR-swizzled
    // [32768,49152):  xT  32 rows x 512B  (bf16 k=256), XOR-swizzled
    // [49152,57344):  ex  [2 m][4 plane][16 row][16 unit] f32 (r,z,xn,hn)

    const int bid = blockIdx.x;
    const int g = bid & 7, l = bid >> 3;
    const int tid = threadIdx.x;
    const int w = tid >> 6, lane = tid & 63;
    const int lr = lane & 15, ko = (lane >> 4) << 3;

    char* hT = lds;
    char* xT = lds + 32768;
    float* ex = (float*)(lds + 49152);

    __bf16* hbf_g = hbf + g * (32 * 512);
    __bf16* xp_g = xp + g * (32 * 256);
    int* cg = cnt + g * 16;  // 64B-spaced counters

    // ---- per-wave persistent weight registers ----
    bf16x8 wHi[16], wLo[16];
    bf16x8 wxf = {};
    float bt_r = 0.f;
    const int mw = (w == 6) ? (l & 1) : (w & 1);  // row-half for this wave
    const int gg = w >> 1;                        // gate (waves 0..5)
    if (w < 6) {
        int j = gg * 512 + l * 16 + lr;
        const __bf16* ph = Whh_hi + (size_t)j * 512 + ko;
        const __bf16* pl = Whh_lo + (size_t)j * 512 + ko;
#pragma unroll
        for (int k0 = 0; k0 < 16; ++k0) {
            wHi[k0] = *(const bf16x8*)(ph + k0 * 32);
            wLo[k0] = *(const bf16x8*)(pl + k0 * 32);
        }
    } else if (w == 6) {
        int c = (l >> 1) * 16 + lr;
        const __bf16* ph = WhT_hi + (size_t)c * 512 + ko;
        const __bf16* pl = WhT_lo + (size_t)c * 512 + ko;
#pragma unroll
        for (int k0 = 0; k0 < 16; ++k0) {
            wHi[k0] = *(const bf16x8*)(ph + k0 * 32);
            wLo[k0] = *(const bf16x8*)(pl + k0 * 32);
        }
        wxf = *(const bf16x8*)(WxTP + (size_t)c * 32 + ko);
        bt_r = b_t[c];
    }

    // phase-B W_ih row pointers (waves 0..5), L2-resident re-reads
    const __bf16* pBh = Wih_hi + (size_t)(gg * 512 + l * 16 + lr) * 256 + ko;
    const __bf16* pBl = Wih_lo + (size_t)(gg * 512 + l * 16 + lr) * 256 + ko;

    // elementwise per-thread state: (row = tid>>4, unit = tid&15)
    const int erow = tid >> 4, eunit = tid & 15;
    float bi0, bi1, bi2, bh0, bh1, bh2;
    {
        int u = l * 16 + eunit;
        bi0 = b_ih[u]; bi1 = b_ih[512 + u]; bi2 = b_ih[1024 + u];
        bh0 = b_hh[u]; bh1 = b_hh[512 + u]; bh2 = b_hh[1024 + u];
    }
    float hreg = 0.f;  // fp32 h carried in-register across all steps
    const int exi = (erow >> 4) * 1024 + (erow & 15) * 16 + eunit;

    // A-fragment LDS addressing (precomputed)
    const int arow = mw * 16 + lr;
    const int swz = (arow & 7) << 4;
    const int abaseH = arow * 1024 + (lane >> 4) * 16;
    const int abaseX = arow * 512 + (lane >> 4) * 16;

    for (int t = 0; t < Tn; ++t) {
        // ---- stage h -> hT (swizzled) ----
#pragma unroll
        for (int e = 0; e < 4; ++e) {
            int r = e * 8 + w;
            bf16x8 v = *(const bf16x8*)(hbf_g + r * 512 + lane * 8);
            int byte = (r * 1024 + lane * 16) ^ ((r & 7) << 4);
            *(bf16x8*)(hT + byte) = v;
        }
        __syncthreads();

        // ---- phase A: gh (waves 0-5) / x' (wave 6), K=512 hi/lo ----
        f32x4 accG = {};
        if (w < 6) {
#pragma unroll
            for (int k0 = 0; k0 < 16; ++k0) {
                bf16x8 a = *(const bf16x8*)(hT + ((abaseH + k0 * 64) ^ swz));
                accG = MFMA(a, wHi[k0], accG);
                accG = MFMA(a, wLo[k0], accG);
            }
        } else if (w == 6) {
#pragma unroll
            for (int k0 = 0; k0 < 16; ++k0) {
                bf16x8 a = *(const bf16x8*)(hT + ((abaseH + k0 * 64) ^ swz));
                accG = MFMA(a, wHi[k0], accG);
                accG = MFMA(a, wLo[k0], accG);
            }
            // xin tail (K=32, hi-only)
            bf16x8 ax = *(const bf16x8*)(XinP +
                ((size_t)t * 256 + g * 32 + mw * 16 + lr) * 32 + ko);
            accG = MFMA(ax, wxf, accG);
            // tanh + store x' (bf16) for group broadcast
            int c = (l >> 1) * 16 + lr;
#pragma unroll
            for (int r = 0; r < 4; ++r) {
                int row = mw * 16 + (lane >> 4) * 4 + r;
                float v = accG[r] + bt_r;
                float e2 = __expf(2.f * v);
                xp_g[row * 256 + c] = (__bf16)(1.f - 2.f / (e2 + 1.f));
            }
        }

        GBAR(32 * (2 * t + 1));  // x' visible group-wide

        // ---- stage x' -> xT (swizzled) ----
#pragma unroll
        for (int e = 0; e < 2; ++e) {
            int r = e * 16 + (tid >> 5);
            int kc = tid & 31;
            bf16x8 v = *(const bf16x8*)(xp_g + r * 256 + kc * 8);
            int byte = (r * 512 + kc * 16) ^ ((r & 7) << 4);
            *(bf16x8*)(xT + byte) = v;
        }
        __syncthreads();

        // ---- phase B: gx = x' @ W_ih.T (waves 0-5), K=256 hi/lo ----
        if (w < 6) {
            f32x4 accX = {};
#pragma unroll
            for (int k0 = 0; k0 < 8; ++k0) {
                bf16x8 a = *(const bf16x8*)(xT + ((abaseX + k0 * 64) ^ swz));
                bf16x8 bh = *(const bf16x8*)(pBh + k0 * 32);
                bf16x8 bl = *(const bf16x8*)(pBl + k0 * 32);
                accX = MFMA(a, bh, accX);
                accX = MFMA(a, bl, accX);
            }
            // write gate pre-acts to exchange LDS
            float* exm = ex + mw * 1024;
            if (gg < 2) {
#pragma unroll
                for (int r = 0; r < 4; ++r)
                    exm[gg * 256 + ((lane >> 4) * 4 + r) * 16 + lr] =
                        accG[r] + accX[r];
            } else {
#pragma unroll
                for (int r = 0; r < 4; ++r) {
                    exm[2 * 256 + ((lane >> 4) * 4 + r) * 16 + lr] = accX[r];
                    exm[3 * 256 + ((lane >> 4) * 4 + r) * 16 + lr] = accG[r];
                }
            }
        }
        __syncthreads();

        // ---- elementwise GRU update (all 512 threads, 1 elem each) ----
        {
            float pr = ex[exi] + bi0 + bh0;
            float pz = ex[exi + 256] + bi1 + bh1;
            float xn = ex[exi + 512] + bi2;
            float hn = ex[exi + 768] + bh2;
            float rr = 1.f / (1.f + __expf(-pr));
            float zz = 1.f / (1.f + __expf(-pz));
            float e2 = __expf(2.f * (xn + rr * hn));
            float nn = 1.f - 2.f / (e2 + 1.f);
            hreg = (1.f - zz) * nn + zz * hreg;
            hbf_g[erow * 512 + l * 16 + eunit] = (__bf16)hreg;
            if (t == Tn - 1)
                out[(size_t)(g * 32 + erow) * 512 + l * 16 + eunit] = hreg;
        }

        if (t != Tn - 1) GBAR(32 * (2 * t + 2));  // h visible group-wide
    }
}

// ---------------- host launcher ----------------

extern "C" void kernel_launch(void* const* d_in, const int* in_sizes, int n_in,
                              void* d_out, int out_size, void* d_ws, size_t ws_size,
                              hipStream_t stream) {
    const float* x_l = (const float*)d_in[0];
    const float* x_e = (const float*)d_in[1];
    const float* Wh  = (const float*)d_in[2];
    const float* Wx  = (const float*)d_in[3];
    const float* bt  = (const float*)d_in[4];
    const float* Wih = (const float*)d_in[5];
    const float* Whh = (const float*)d_in[6];
    const float* bih = (const float*)d_in[7];
    const float* bhh = (const float*)d_in[8];

    char* ws = (char*)d_ws;
    __bf16* WhT_hi = (__bf16*)(ws + 0);          //  262144
    __bf16* WhT_lo = (__bf16*)(ws + 262144);     //  262144
    __bf16* WxTP   = (__bf16*)(ws + 524288);     //   16384
    __bf16* Wih_hi = (__bf16*)(ws + 540672);     //  786432
    __bf16* Wih_lo = (__bf16*)(ws + 1327104);    //  786432
    __bf16* Whh_hi = (__bf16*)(ws + 2113536);    // 1572864
    __bf16* Whh_lo = (__bf16*)(ws + 3686400);    // 1572864
    __bf16* XinP   = (__bf16*)(ws + 5259264);    // 5505024
    __bf16* xp     = (__bf16*)(ws + 10764288);   //  131072
    __bf16* hbf    = (__bf16*)(ws + 10895360);   //  262144
    int*    cnt    = (int*)   (ws + 11157504);   //     512  -> total ~11.2 MB

    // one-time packing (graph-captured, cheap)
    pack_wh<<<512, 256, 0, stream>>>(Wh, WhT_hi, WhT_lo);
    pack_wx<<<32, 256, 0, stream>>>(Wx, WxTP);
    pack_split<<<1536, 256, 0, stream>>>(Wih, Wih_hi, Wih_lo, 1536 * 256);
    pack_split<<<3072, 256, 0, stream>>>(Whh, Whh_hi, Whh_lo, 1536 * 512);
    pack_xin<<<10752, 256, 0, stream>>>(x_l, x_e, XinP);
    hipMemsetAsync(hbf, 0, 262144, stream);
    hipMemsetAsync(cnt, 0, 512, stream);

    gru_persist<<<256, 512, 0, stream>>>(
        WhT_hi, WhT_lo, WxTP, Wih_hi, Wih_lo, Whh_hi, Whh_lo, XinP,
        bt, bih, bhh, xp, hbf, cnt, (float*)d_out);
}

// Round 5
// 2636.783 us; speedup vs baseline: 18.9642x; 18.9642x over previous
//
#include <hip/hip_runtime.h>
#include <hip/hip_bf16.h>

// Problem constants
#define Bn 256
#define Tn 336
#define KE 16

typedef __attribute__((ext_vector_type(8))) __bf16 bf16x8;
typedef __attribute__((ext_vector_type(4))) float f32x4;
typedef unsigned long long u64t;

#define MFMA(a, b, c) __builtin_amdgcn_mfma_f32_16x16x32_bf16((a), (b), (c), 0, 0, 0)

// ---------------- pack kernels (once per launch) ----------------

__global__ void pack_wh(const float* __restrict__ Wh, __bf16* __restrict__ hi,
                        __bf16* __restrict__ lo) {
    int i = blockIdx.x * 256 + threadIdx.x;  // 512*256
    int k = i >> 8, n = i & 255;
    float v = Wh[i];
    __bf16 h = (__bf16)v;
    hi[n * 512 + k] = h;
    lo[n * 512 + k] = (__bf16)(v - (float)h);
}

__global__ void pack_wx(const float* __restrict__ Wx, __bf16* __restrict__ out) {
    int i = blockIdx.x * 256 + threadIdx.x;  // 256*32
    int n = i >> 5, k = i & 31;
    out[i] = (__bf16)((k < 17) ? Wx[k * 256 + n] : 0.f);
}

__global__ void pack_split(const float* __restrict__ in, __bf16* __restrict__ hi,
                           __bf16* __restrict__ lo, int n) {
    int i = blockIdx.x * 256 + threadIdx.x;
    if (i >= n) return;
    float v = in[i];
    __bf16 h = (__bf16)v;
    hi[i] = h;
    lo[i] = (__bf16)(v - (float)h);
}

__global__ void pack_xin(const float* __restrict__ xl, const float* __restrict__ xe,
                         __bf16* __restrict__ out) {
    int i = blockIdx.x * 256 + threadIdx.x;  // 336*256*32
    int k = i & 31, b = (i >> 5) & 255, t = i >> 13;
    float v = 0.f;
    if (k == 0) v = xl[b * Tn + t];
    else if (k < 17) v = xe[(b * Tn + t) * KE + (k - 1)];
    out[i] = (__bf16)v;
}

// ---------------- MALL-coherent helpers (relaxed agent = sc1, NO cache
// maintenance — avoids the L2 invalidate/writeback storms of acq/rel) -------

__device__ __forceinline__ bf16x8 ld16_mall(const __bf16* p) {
    union { u64t q[2]; bf16x8 v; } r;
    const u64t* q = (const u64t*)p;
    r.q[0] = __hip_atomic_load(q, __ATOMIC_RELAXED, __HIP_MEMORY_SCOPE_AGENT);
    r.q[1] = __hip_atomic_load(q + 1, __ATOMIC_RELAXED, __HIP_MEMORY_SCOPE_AGENT);
    return r.v;
}

__device__ __forceinline__ void st2_mall(__bf16* p, float f) {
    __bf16 h = (__bf16)f;
    union { __bf16 b; unsigned short u; } c; c.b = h;
    __hip_atomic_store((unsigned short*)p, c.u, __ATOMIC_RELAXED,
                       __HIP_MEMORY_SCOPE_AGENT);
}

// group barrier: __syncthreads() drains vmcnt(0) before s_barrier, so all
// prior sc1 stores are MALL-visible before the counter bump. No fences.
#define GBAR(TGT)                                                              \
    do {                                                                       \
        __syncthreads();                                                       \
        if (tid == 0) {                                                        \
            __hip_atomic_fetch_add(cg, 1, __ATOMIC_RELAXED,                    \
                                   __HIP_MEMORY_SCOPE_AGENT);                  \
            while (__hip_atomic_load(cg, __ATOMIC_RELAXED,                     \
                                     __HIP_MEMORY_SCOPE_AGENT) < (TGT)) {      \
                __builtin_amdgcn_s_sleep(2);                                   \
            }                                                                  \
        }                                                                      \
        __syncthreads();                                                       \
    } while (0)

// ---------------- persistent GRU kernel ----------------
// grid = 256 blocks, block = 512 threads (8 waves). group g = bid&7
// (32 blocks, batch rows [g*32, g*32+32)); block l = bid>>3 owns hidden
// units [16l,16l+16). Waves 0..5: (gate=w>>1, row-half=w&1) with W_hh
// fragments pinned in registers; wave 6: x' tile with Wh fragments in
// registers; wave 7: staging/elementwise only.

__global__ __launch_bounds__(512, 2)
__attribute__((amdgpu_waves_per_eu(2, 2)))
void gru_persist(
    const __bf16* __restrict__ WhT_hi, const __bf16* __restrict__ WhT_lo,
    const __bf16* __restrict__ WxTP,
    const __bf16* __restrict__ Wih_hi, const __bf16* __restrict__ Wih_lo,
    const __bf16* __restrict__ Whh_hi, const __bf16* __restrict__ Whh_lo,
    const __bf16* __restrict__ XinP,
    const float* __restrict__ b_t, const float* __restrict__ b_ih,
    const float* __restrict__ b_hh,
    __bf16* xp, __bf16* hbf,  // shared via MALL-coherent ops
    int* cnt, float* __restrict__ out)
{
    __shared__ __align__(16) char lds[57344];
    // [0,32768):      hT  32 rows x 1024B (bf16 k=512), XOR-swizzled
    // [32768,49152):  xT  32 rows x 512B  (bf16 k=256), XOR-swizzled
    // [49152,57344):  ex  [2 half][4 plane][16 row][16 unit] f32

    const int bid = blockIdx.x;
    const int g = bid & 7, l = bid >> 3;
    const int tid = threadIdx.x;
    const int w = tid >> 6, lane = tid & 63;
    const int lr = lane & 15, ko = (lane >> 4) << 3;

    char* hT = lds;
    char* xT = lds + 32768;
    float* ex = (float*)(lds + 49152);

    __bf16* hbf_g = hbf + g * (32 * 512);
    __bf16* xp_g  = xp  + g * (32 * 256);
    int* cg = cnt + g * 16;  // 64B-spaced counters

    const int mw = (w == 6) ? (l & 1) : (w & 1);  // row-half for this wave
    const int gg = (w < 6) ? (w >> 1) : 0;        // gate (waves 0..5)

    // ---- persistent phase-A weights in registers (uniform-shape init) ----
    const __bf16 *srcH, *srcL;
    if (w < 6) {
        size_t j = (size_t)(gg * 512 + l * 16 + lr) * 512 + ko;
        srcH = Whh_hi + j; srcL = Whh_lo + j;
    } else if (w == 6) {
        size_t j = (size_t)((l >> 1) * 16 + lr) * 512 + ko;
        srcH = WhT_hi + j; srcL = WhT_lo + j;
    } else {
        srcH = Whh_hi + ko; srcL = Whh_lo + ko;  // dummy (valid) for wave 7
    }
    bf16x8 wHi[16], wLo[16];
#pragma unroll
    for (int k0 = 0; k0 < 16; ++k0) {
        wHi[k0] = *(const bf16x8*)(srcH + k0 * 32);
        wLo[k0] = *(const bf16x8*)(srcL + k0 * 32);
    }
    bf16x8 wxf = {};
    float bt_r = 0.f;
    if (w == 6) {
        int c = (l >> 1) * 16 + lr;
        wxf = *(const bf16x8*)(WxTP + (size_t)c * 32 + ko);
        bt_r = b_t[c];
    }

    // phase-B W_ih row pointers (waves 0..5), cacheable L2-resident re-reads
    const __bf16* pBh = Wih_hi + (size_t)(gg * 512 + l * 16 + lr) * 256 + ko;
    const __bf16* pBl = Wih_lo + (size_t)(gg * 512 + l * 16 + lr) * 256 + ko;

    // elementwise per-thread state: (row = tid>>4, unit = tid&15)
    const int erow = tid >> 4, eunit = tid & 15;
    float bi0, bi1, bi2, bh0, bh1, bh2;
    {
        int u = l * 16 + eunit;
        bi0 = b_ih[u]; bi1 = b_ih[512 + u]; bi2 = b_ih[1024 + u];
        bh0 = b_hh[u]; bh1 = b_hh[512 + u]; bh2 = b_hh[1024 + u];
    }
    float hreg = 0.f;  // fp32 h carried in-register across all steps
    const int exi = (erow >> 4) * 1024 + (erow & 15) * 16 + eunit;

    const int arow = mw * 16 + lr;
    const int swz = (arow & 7) << 4;
    const int abaseH = arow * 1024 + (lane >> 4) * 16;
    const int abaseX = arow * 512 + (lane >> 4) * 16;

    for (int t = 0; t < Tn; ++t) {
        // ---- stage h -> hT (swizzled), MALL-coherent reads ----
#pragma unroll
        for (int e = 0; e < 4; ++e) {
            int r = e * 8 + w;
            bf16x8 v = ld16_mall(hbf_g + r * 512 + lane * 8);
            *(bf16x8*)(hT + ((r * 1024 + lane * 16) ^ ((r & 7) << 4))) = v;
        }
        __syncthreads();

        // ---- phase A: gh (waves 0-5) / x' (wave 6), K=512 hi/lo ----
        f32x4 accG = {};
        if (w < 7) {
#pragma unroll
            for (int k0 = 0; k0 < 16; ++k0) {
                bf16x8 a = *(const bf16x8*)(hT + ((abaseH + k0 * 64) ^ swz));
                accG = MFMA(a, wHi[k0], accG);
                accG = MFMA(a, wLo[k0], accG);
            }
        }
        if (w == 6) {
            bf16x8 ax = *(const bf16x8*)(XinP +
                ((size_t)t * 256 + g * 32 + mw * 16 + lr) * 32 + ko);
            accG = MFMA(ax, wxf, accG);
            int c = (l >> 1) * 16 + lr;
#pragma unroll
            for (int r = 0; r < 4; ++r) {
                int row = mw * 16 + (lane >> 4) * 4 + r;
                float v = accG[r] + bt_r;
                float e2 = __expf(2.f * v);
                st2_mall(xp_g + row * 256 + c, 1.f - 2.f / (e2 + 1.f));
            }
        }

        GBAR(32 * (2 * t + 1));  // x' MALL-visible group-wide

        // ---- stage x' -> xT (swizzled), MALL-coherent reads ----
#pragma unroll
        for (int e = 0; e < 2; ++e) {
            int r = e * 16 + (tid >> 5);
            int kc = tid & 31;
            bf16x8 v = ld16_mall(xp_g + r * 256 + kc * 8);
            *(bf16x8*)(xT + ((r * 512 + kc * 16) ^ ((r & 7) << 4))) = v;
        }
        __syncthreads();

        // ---- phase B: gx = x' @ W_ih.T (waves 0-5), K=256 hi/lo ----
        if (w < 6) {
            f32x4 accX = {};
#pragma unroll
            for (int k0 = 0; k0 < 8; ++k0) {
                bf16x8 a = *(const bf16x8*)(xT + ((abaseX + k0 * 64) ^ swz));
                bf16x8 bh = *(const bf16x8*)(pBh + k0 * 32);
                bf16x8 bl = *(const bf16x8*)(pBl + k0 * 32);
                accX = MFMA(a, bh, accX);
                accX = MFMA(a, bl, accX);
            }
            float* exm = ex + mw * 1024;
            if (gg < 2) {
#pragma unroll
                for (int r = 0; r < 4; ++r)
                    exm[gg * 256 + ((lane >> 4) * 4 + r) * 16 + lr] =
                        accG[r] + accX[r];
            } else {
#pragma unroll
                for (int r = 0; r < 4; ++r) {
                    exm[2 * 256 + ((lane >> 4) * 4 + r) * 16 + lr] = accX[r];
                    exm[3 * 256 + ((lane >> 4) * 4 + r) * 16 + lr] = accG[r];
                }
            }
        }
        __syncthreads();

        // ---- elementwise GRU update (all 512 threads, 1 elem each) ----
        {
            float pr = ex[exi]       + bi0 + bh0;
            float pz = ex[exi + 256] + bi1 + bh1;
            float xn = ex[exi + 512] + bi2;
            float hn = ex[exi + 768] + bh2;
            float rr = 1.f / (1.f + __expf(-pr));
            float zz = 1.f / (1.f + __expf(-pz));
            float e2 = __expf(2.f * (xn + rr * hn));
            float nn = 1.f - 2.f / (e2 + 1.f);
            hreg = (1.f - zz) * nn + zz * hreg;
            st2_mall(hbf_g + erow * 512 + l * 16 + eunit, hreg);
            if (t == Tn - 1)
                out[(size_t)(g * 32 + erow) * 512 + l * 16 + eunit] = hreg;
        }

        if (t != Tn - 1) GBAR(32 * (2 * t + 2));  // h MALL-visible group-wide
    }
}

// ---------------- host launcher ----------------

extern "C" void kernel_launch(void* const* d_in, const int* in_sizes, int n_in,
                              void* d_out, int out_size, void* d_ws, size_t ws_size,
                              hipStream_t stream) {
    const float* x_l = (const float*)d_in[0];
    const float* x_e = (const float*)d_in[1];
    const float* Wh  = (const float*)d_in[2];
    const float* Wx  = (const float*)d_in[3];
    const float* bt  = (const float*)d_in[4];
    const float* Wih = (const float*)d_in[5];
    const float* Whh = (const float*)d_in[6];
    const float* bih = (const float*)d_in[7];
    const float* bhh = (const float*)d_in[8];

    char* ws = (char*)d_ws;
    __bf16* WhT_hi = (__bf16*)(ws + 0);          //  262144
    __bf16* WhT_lo = (__bf16*)(ws + 262144);     //  262144
    __bf16* WxTP   = (__bf16*)(ws + 524288);     //   16384
    __bf16* Wih_hi = (__bf16*)(ws + 540672);     //  786432
    __bf16* Wih_lo = (__bf16*)(ws + 1327104);    //  786432
    __bf16* Whh_hi = (__bf16*)(ws + 2113536);    // 1572864
    __bf16* Whh_lo = (__bf16*)(ws + 3686400);    // 1572864
    __bf16* XinP   = (__bf16*)(ws + 5259264);    // 5505024
    __bf16* xp     = (__bf16*)(ws + 10764288);   //  131072
    __bf16* hbf    = (__bf16*)(ws + 10895360);   //  262144
    int*    cnt    = (int*)   (ws + 11157504);   //     512  -> total ~11.2 MB

    pack_wh<<<512, 256, 0, stream>>>(Wh, WhT_hi, WhT_lo);
    pack_wx<<<32, 256, 0, stream>>>(Wx, WxTP);
    pack_split<<<1536, 256, 0, stream>>>(Wih, Wih_hi, Wih_lo, 1536 * 256);
    pack_split<<<3072, 256, 0, stream>>>(Whh, Whh_hi, Whh_lo, 1536 * 512);
    pack_xin<<<10752, 256, 0, stream>>>(x_l, x_e, XinP);
    hipMemsetAsync(hbf, 0, 262144, stream);
    hipMemsetAsync(cnt, 0, 512, stream);

    gru_persist<<<256, 512, 0, stream>>>(
        WhT_hi, WhT_lo, WxTP, Wih_hi, Wih_lo, Whh_hi, Whh_lo, XinP,
        bt, bih, bhh, xp, hbf, cnt, (float*)d_out);
}